// Round 11
// baseline (733.123 us; speedup 1.0000x reference)
//
#include <hip/hip_runtime.h>
#include <math.h>

#define N_NODES 50000
#define N_EDGES 800000
#define N_TOT   850000   // edges + self loops
#define NSB     ((N_NODES + 255) / 256)   // scan blocks = 196

typedef __attribute__((ext_vector_type(8))) short short8;   // 8 bf16 (4 VGPRs)
typedef __attribute__((ext_vector_type(4))) float floatx4;  // MFMA acc

// ---------------------------- bf16 pack/unpack ------------------------------
__device__ __forceinline__ unsigned int pack_bf16x2(float a, float b) {
    unsigned ua = __float_as_uint(a);
    unsigned ub = __float_as_uint(b);
    ua += 0x7fff + ((ua >> 16) & 1);   // round-to-nearest-even
    ub += 0x7fff + ((ub >> 16) & 1);
    return (ua >> 16) | (ub & 0xffff0000u);
}
__device__ __forceinline__ unsigned short pack_bf16(float a) {
    unsigned ua = __float_as_uint(a);
    ua += 0x7fff + ((ua >> 16) & 1);
    return (unsigned short)(ua >> 16);
}
__device__ __forceinline__ float bf16_lo(unsigned u) { return __uint_as_float(u << 16); }
__device__ __forceinline__ float bf16_hi(unsigned u) { return __uint_as_float(u & 0xffff0000u); }

// ----------------------------- utility kernels -----------------------------
__global__ void zero_int_kernel(int* p, int n) {
    int i = blockIdx.x * blockDim.x + threadIdx.x;
    if (i < n) p[i] = 0;
}

// ----------------------------- CSR build -----------------------------------
__global__ void deg_hist_kernel(const int* __restrict__ ei, int* __restrict__ deg) {
    int e = blockIdx.x * blockDim.x + threadIdx.x;
    if (e >= N_TOT) return;
    int dst = (e < N_EDGES) ? ei[N_EDGES + e] : (e - N_EDGES);
    atomicAdd(&deg[dst], 1);
}

__global__ void block_scan_kernel(const int* __restrict__ deg, int* __restrict__ part,
                                  int* __restrict__ bsum) {
    __shared__ int tmp[256];
    int t = threadIdx.x;
    int i = blockIdx.x * 256 + t;
    int v = (i < N_NODES) ? deg[i] : 0;
    tmp[t] = v;
    __syncthreads();
    for (int d = 1; d < 256; d <<= 1) {
        int u = (t >= d) ? tmp[t - d] : 0;
        __syncthreads();
        tmp[t] += u;
        __syncthreads();
    }
    if (i < N_NODES) part[i] = tmp[t] - v;   // exclusive
    if (t == 255) bsum[blockIdx.x] = tmp[255];
}

__global__ void scan_bsum_kernel(int* __restrict__ bsum) {
    __shared__ int tmp[256];
    int t = threadIdx.x;
    int v = (t < NSB) ? bsum[t] : 0;
    tmp[t] = v;
    __syncthreads();
    for (int d = 1; d < 256; d <<= 1) {
        int u = (t >= d) ? tmp[t - d] : 0;
        __syncthreads();
        tmp[t] += u;
        __syncthreads();
    }
    if (t < NSB) bsum[t] = tmp[t] - v;       // exclusive block offsets
}

__global__ void finalize_off_kernel(const int* __restrict__ part, const int* __restrict__ bsum,
                                    int* __restrict__ off, int* __restrict__ cursor) {
    int i = blockIdx.x * 256 + threadIdx.x;
    if (i < N_NODES) {
        int o = part[i] + bsum[blockIdx.x];
        off[i] = o;
        cursor[i] = o;
    }
    if (i == 0) off[N_NODES] = N_TOT;
}

__global__ void fill_csr_kernel(const int* __restrict__ ei, int* __restrict__ cursor,
                                int* __restrict__ csr_src) {
    int e = blockIdx.x * blockDim.x + threadIdx.x;
    if (e >= N_TOT) return;
    int src, dst;
    if (e < N_EDGES) { src = ei[e]; dst = ei[N_EDGES + e]; }
    else             { src = dst = e - N_EDGES; }
    int pos = atomicAdd(&cursor[dst], 1);
    csr_src[pos] = src;
}

// --------------- weight convert: W [K][N] fp32 -> Wt [N][K] bf16 ------------
__global__ void wconv_kernel(const float* __restrict__ W1, const float* __restrict__ W2,
                             const float* __restrict__ W3, const float* __restrict__ W4,
                             unsigned short* __restrict__ T1, unsigned short* __restrict__ T2,
                             unsigned short* __restrict__ T3, unsigned short* __restrict__ T4) {
    int i = blockIdx.x * 256 + threadIdx.x;
    const float* W; unsigned short* T; int K, N, idx;
    if      (i < 32768) { W = W1; T = T1; K = 128; N = 256; idx = i; }
    else if (i < 40960) { W = W2; T = T2; K = 256; N = 32;  idx = i - 32768; }
    else if (i < 49152) { W = W3; T = T3; K = 32;  N = 256; idx = i - 40960; }
    else if (i < 81920) { W = W4; T = T4; K = 256; N = 128; idx = i - 49152; }
    else return;
    int n = idx / K, k = idx % K;
    T[idx] = pack_bf16(W[(size_t)k * N + n]);
}

// ------------------ fused MFMA GEMM + attention logits ----------------------
// Block = 256 threads (4 waves), NPB nodes x Cout channels.
// A staged to LDS bf16 (row pad +8 -> aligned b128 fragments); B from Wt
// [Cout][Cin] bf16 global (L2-hot). K-loop of mfma_f32_16x16x32_bf16.
// Epilogue: C -> LDS as bf16 (UNION with A buffer; halves LDS, keeps
// occupancy), then thread-per-(node,16ch): 1 uint4 LDS read -> 1 coalesced
// uint4 global store + logits dot (shfl-reduce across C/16 threads).
template<int Cin, int Cout, int H, int C, int NPB, int NW_N, bool IN_BF16>
__global__ void gemm_mfma_kernel(const void* __restrict__ xin,
                                 const unsigned short* __restrict__ Wt,
                                 const float* __restrict__ a_src, const float* __restrict__ a_dst,
                                 unsigned short* __restrict__ hb,
                                 float* __restrict__ al_s, float* __restrict__ al_d) {
    constexpr int NW_M = 4 / NW_N;
    constexpr int MT_W = (NPB / 16) / NW_M;   // m-tiles per wave
    constexpr int NT_W = (Cout / 16) / NW_N;  // n-tiles per wave
    constexpr int AS   = Cin + 8;             // A row stride (bf16 elems)
    constexpr int HS   = Cout + 8;            // C row stride (bf16 elems)
    constexpr size_t SMEM_EL = (size_t)NPB * ((AS > HS) ? AS : HS);
    __shared__ uint4 smem_raw[(SMEM_EL * 2 + 15) / 16];
    unsigned short* xs  = (unsigned short*)smem_raw;
    unsigned short* hsb = (unsigned short*)smem_raw;   // union: reused after K-loop
    int tid = threadIdx.x;
    int n0  = blockIdx.x * NPB;

    // ---- stage A tile as bf16 ----
    if (IN_BF16) {
        for (int i = tid; i < NPB * Cin / 8; i += 256) {
            int n = i / (Cin / 8), k8 = i % (Cin / 8);
            uint4 q = make_uint4(0u, 0u, 0u, 0u);
            if (n0 + n < N_NODES)
                q = ((const uint4*)((const unsigned short*)xin + (size_t)(n0 + n) * Cin))[k8];
            *(uint4*)(xs + n * AS + k8 * 8) = q;
        }
    } else {
        for (int i = tid; i < NPB * Cin / 4; i += 256) {
            int n = i / (Cin / 4), k4 = i % (Cin / 4);
            float4 v = make_float4(0.f, 0.f, 0.f, 0.f);
            if (n0 + n < N_NODES)
                v = ((const float4*)((const float*)xin + (size_t)(n0 + n) * Cin))[k4];
            uint2 p;
            p.x = pack_bf16x2(v.x, v.y);
            p.y = pack_bf16x2(v.z, v.w);
            *(uint2*)(xs + n * AS + k4 * 4) = p;
        }
    }
    __syncthreads();

    int w = tid >> 6, lane = tid & 63;
    int q = lane >> 4, l16 = lane & 15;
    int wm = w / NW_N, wn = w % NW_N;
    int mbase = wm * MT_W * 16;
    int nbase = wn * NT_W * 16;

    floatx4 acc[MT_W][NT_W];
#pragma unroll
    for (int mt = 0; mt < MT_W; mt++)
#pragma unroll
        for (int nt = 0; nt < NT_W; nt++) acc[mt][nt] = (floatx4){0.f, 0.f, 0.f, 0.f};

#pragma unroll
    for (int k0 = 0; k0 < Cin; k0 += 32) {
        short8 a[MT_W], b[NT_W];
#pragma unroll
        for (int mt = 0; mt < MT_W; mt++)
            a[mt] = *(const short8*)(xs + (mbase + mt * 16 + l16) * AS + k0 + q * 8);
#pragma unroll
        for (int nt = 0; nt < NT_W; nt++)
            b[nt] = *(const short8*)(Wt + (size_t)(nbase + nt * 16 + l16) * Cin + k0 + q * 8);
#pragma unroll
        for (int mt = 0; mt < MT_W; mt++)
#pragma unroll
            for (int nt = 0; nt < NT_W; nt++)
                acc[mt][nt] = __builtin_amdgcn_mfma_f32_16x16x32_bf16(a[mt], b[nt], acc[mt][nt], 0, 0, 0);
    }
    __syncthreads();   // all xs reads done before hsb overwrites the union

    // ---- C tiles -> LDS bf16 (row = q*4 + reg, col = l16) ----
#pragma unroll
    for (int mt = 0; mt < MT_W; mt++)
#pragma unroll
        for (int nt = 0; nt < NT_W; nt++)
#pragma unroll
            for (int r = 0; r < 4; r++) {
                int nl = mbase + mt * 16 + q * 4 + r;
                int ch = nbase + nt * 16 + l16;
                hsb[nl * HS + ch] = pack_bf16(acc[mt][nt][r]);
            }
    __syncthreads();

    // ---- epilogue: thread-per-(node,16ch): h store + logits ----
    constexpr int TPN = Cout / 16;       // threads per node
    constexpr int TPH = C / 16;          // threads per head
    for (int t = tid; t < NPB * TPN; t += 256) {
        int nodeL = t / TPN, sub = t % TPN;
        int gn = n0 + nodeL;
        uint4 qv = *(const uint4*)(hsb + nodeL * HS + sub * 16);
        int head = (sub * 16) / C;
        int coff = (sub * 16) % C;
        const float4* ap = (const float4*)(a_src + head * C + coff);
        const float4* dp = (const float4*)(a_dst + head * C + coff);
        float hv[16];
        hv[0] = bf16_lo(qv.x); hv[1] = bf16_hi(qv.x);
        hv[2] = bf16_lo(qv.y); hv[3] = bf16_hi(qv.y);
        hv[4] = bf16_lo(qv.z); hv[5] = bf16_hi(qv.z);
        hv[6] = bf16_lo(qv.w); hv[7] = bf16_hi(qv.w);
        uint4 qv2 = *(const uint4*)(hsb + nodeL * HS + sub * 16 + 8);
        hv[8]  = bf16_lo(qv2.x); hv[9]  = bf16_hi(qv2.x);
        hv[10] = bf16_lo(qv2.y); hv[11] = bf16_hi(qv2.y);
        hv[12] = bf16_lo(qv2.z); hv[13] = bf16_hi(qv2.z);
        hv[14] = bf16_lo(qv2.w); hv[15] = bf16_hi(qv2.w);
        float ps = 0.f, pd = 0.f;
#pragma unroll
        for (int c4 = 0; c4 < 4; c4++) {
            float4 av = ap[c4], dv = dp[c4];
            ps += hv[c4*4+0]*av.x + hv[c4*4+1]*av.y + hv[c4*4+2]*av.z + hv[c4*4+3]*av.w;
            pd += hv[c4*4+0]*dv.x + hv[c4*4+1]*dv.y + hv[c4*4+2]*dv.z + hv[c4*4+3]*dv.w;
        }
        if (gn < N_NODES) {
            uint4* dst = (uint4*)(hb + (size_t)gn * Cout);
            dst[sub * 2]     = qv;
            dst[sub * 2 + 1] = qv2;
        }
        if (TPH > 1) {
#pragma unroll
            for (int k = 1; k < TPH; k <<= 1) {
                ps += __shfl_xor(ps, k, 64);
                pd += __shfl_xor(pd, k, 64);
            }
        }
        if ((sub % TPH) == 0 && gn < N_NODES) {
            al_s[gn * H + head] = ps;
            al_d[gn * H + head] = pd;
        }
    }
}

// ------------------------- GAT softmax + aggregation ------------------------
// One group of G = H*C/8 lanes per node; each lane owns 8 output channels
// (one uint4 = 16 B bf16 per edge). A 64-lane wave covers NPW = 64/G nodes,
// so one gather instruction serves one edge of EACH of its nodes (half the
// VMEM issue per node-edge vs uint2/G=HC/4). head = g/SUB, SUB = C/8.
// Phase 1: lane reduces only its own head, edges strided by SUB; butterfly.
// Phase 2: uniform edge loop, batches of 8; no cross-lane ops.
template<int H, int C, bool RELU, bool OUT_BF16>
__launch_bounds__(256, 8)
__global__ void gat_agg_kernel(const unsigned short* __restrict__ hb,
                               const float* __restrict__ al_s,
                               const float* __restrict__ al_d, const int* __restrict__ off,
                               const int* __restrict__ csr_src, const float* __restrict__ bias,
                               void* __restrict__ out) {
    constexpr int HC  = H * C;
    constexpr int G   = HC / 8;    // lanes per node (32 / 16 / 4)
    constexpr int SUB = C / 8;     // lanes per head
    constexpr int NPW = 64 / G;    // nodes per wave (2 / 4 / 16)
    constexpr int NPB = 4 * NPW;

    int tid  = threadIdx.x;
    int wid  = tid >> 6;
    int lane = tid & 63;
    int gi   = lane / G;           // node slot within wave
    int g    = lane % G;           // lane within node group
    int node = blockIdx.x * NPB + wid * NPW + gi;
    if (node >= N_NODES) return;

    int head = g / SUB;
    int es   = g % SUB;
    int r0 = off[node], r1 = off[node + 1];
    float ald = al_d[node * H + head];

    // ---- phase 1: online softmax for OWN head, edges strided by SUB ----
    float m = -INFINITY, s = 0.f;
    for (int j = r0 + es; j < r1; j += SUB) {
        int src = csr_src[j];
        float e = al_s[src * H + head] + ald;
        e = (e > 0.f) ? e : 0.2f * e;
        float M = fmaxf(m, e);
        s = s * __expf(m - M) + __expf(e - M);
        m = M;
    }
#pragma unroll
    for (int k = 1; k < SUB; k <<= 1) {
        float om = __shfl_xor(m, k, 64);
        float os = __shfl_xor(s, k, 64);
        float M = fmaxf(m, om);
        float S;
        if (M == -INFINITY) S = 0.f;   // guard NaN from (-inf) - (-inf)
        else S = s * __expf(m - M) + os * __expf(om - M);
        m = M; s = S;
    }
    float inv_s = 1.f / s;             // s >= 1: every node has a self loop

    // ---- phase 2: uniform edge loop, batches of 8, no cross-lane ops ----
    const uint4* hb4 = (const uint4*)hb;
    float a0, a1, a2, a3, a4, a5, a6, a7;
    {
        const float4* bp = (const float4*)(bias + 8 * g);
        float4 b0 = bp[0], b1 = bp[1];
        a0 = b0.x; a1 = b0.y; a2 = b0.z; a3 = b0.w;
        a4 = b1.x; a5 = b1.y; a6 = b1.z; a7 = b1.w;
    }
    int j0 = r0;
    for (; j0 + 8 <= r1; j0 += 8) {
        int srcs[8];
#pragma unroll
        for (int u = 0; u < 8; u++) srcs[u] = csr_src[j0 + u];
#pragma unroll
        for (int u = 0; u < 8; u++) {
            float e = al_s[srcs[u] * H + head] + ald;
            e = (e > 0.f) ? e : 0.2f * e;
            float we = __expf(e - m) * inv_s;
            uint4 qv = hb4[(size_t)srcs[u] * G + g];
            a0 += we * bf16_lo(qv.x); a1 += we * bf16_hi(qv.x);
            a2 += we * bf16_lo(qv.y); a3 += we * bf16_hi(qv.y);
            a4 += we * bf16_lo(qv.z); a5 += we * bf16_hi(qv.z);
            a6 += we * bf16_lo(qv.w); a7 += we * bf16_hi(qv.w);
        }
    }
    for (; j0 < r1; j0++) {
        int src = csr_src[j0];
        float e = al_s[src * H + head] + ald;
        e = (e > 0.f) ? e : 0.2f * e;
        float we = __expf(e - m) * inv_s;
        uint4 qv = hb4[(size_t)src * G + g];
        a0 += we * bf16_lo(qv.x); a1 += we * bf16_hi(qv.x);
        a2 += we * bf16_lo(qv.y); a3 += we * bf16_hi(qv.y);
        a4 += we * bf16_lo(qv.z); a5 += we * bf16_hi(qv.z);
        a6 += we * bf16_lo(qv.w); a7 += we * bf16_hi(qv.w);
    }
    if (RELU) {
        a0 = fmaxf(a0, 0.f); a1 = fmaxf(a1, 0.f); a2 = fmaxf(a2, 0.f); a3 = fmaxf(a3, 0.f);
        a4 = fmaxf(a4, 0.f); a5 = fmaxf(a5, 0.f); a6 = fmaxf(a6, 0.f); a7 = fmaxf(a7, 0.f);
    }
    if (OUT_BF16) {
        uint4 p;
        p.x = pack_bf16x2(a0, a1); p.y = pack_bf16x2(a2, a3);
        p.z = pack_bf16x2(a4, a5); p.w = pack_bf16x2(a6, a7);
        ((uint4*)out)[(size_t)node * G + g] = p;
    } else {
        float4* op = (float4*)out + (size_t)node * (HC / 4) + 2 * g;
        op[0] = make_float4(a0, a1, a2, a3);
        op[1] = make_float4(a4, a5, a6, a7);
    }
}

// ------------------------------- launcher -----------------------------------
extern "C" void kernel_launch(void* const* d_in, const int* in_sizes, int n_in,
                              void* d_out, int out_size, void* d_ws, size_t ws_size,
                              hipStream_t stream) {
    const float* x   = (const float*)d_in[0];
    const int*   ei  = (const int*)d_in[1];   // harness casts int64 -> int32
    const float* W1  = (const float*)d_in[2];
    const float* as1 = (const float*)d_in[3];
    const float* ad1 = (const float*)d_in[4];
    const float* b1  = (const float*)d_in[5];
    const float* W2  = (const float*)d_in[6];
    const float* as2 = (const float*)d_in[7];
    const float* ad2 = (const float*)d_in[8];
    const float* b2  = (const float*)d_in[9];
    const float* W3  = (const float*)d_in[10];
    const float* as3 = (const float*)d_in[11];
    const float* ad3 = (const float*)d_in[12];
    const float* b3  = (const float*)d_in[13];
    const float* W4  = (const float*)d_in[14];
    const float* as4 = (const float*)d_in[15];
    const float* ad4 = (const float*)d_in[16];
    const float* b4  = (const float*)d_in[17];

    char* ws = (char*)d_ws;
    size_t o = 0;
    auto alloc = [&](size_t bytes) -> void* {
        void* p = ws + o;
        o = (o + bytes + 255) & ~(size_t)255;
        return p;
    };
    unsigned short* feat_a  = (unsigned short*)alloc((size_t)N_NODES * 256 * 2); // 25.6 MB bf16
    unsigned short* feat_b  = (unsigned short*)alloc((size_t)N_NODES * 32 * 2);  // 3.2 MB bf16
    unsigned short* h_buf   = (unsigned short*)alloc((size_t)N_NODES * 256 * 2); // 25.6 MB bf16
    float*          al_s    = (float*)alloc((size_t)N_NODES * 8 * 4);
    float*          al_d    = (float*)alloc((size_t)N_NODES * 8 * 4);
    int*            deg     = (int*)alloc((size_t)(N_NODES + 1) * 4);
    int*            off     = (int*)alloc((size_t)(N_NODES + 1) * 4);
    int*            cursor  = (int*)alloc((size_t)N_NODES * 4);
    int*            part    = (int*)alloc((size_t)N_NODES * 4);
    int*            bsum    = (int*)alloc((size_t)256 * 4);
    int*            csr_src = (int*)alloc((size_t)N_TOT * 4);
    unsigned short* w1t     = (unsigned short*)alloc(32768 * 2);  // [256][128]
    unsigned short* w2t     = (unsigned short*)alloc(8192 * 2);   // [32][256]
    unsigned short* w3t     = (unsigned short*)alloc(8192 * 2);   // [256][32]
    unsigned short* w4t     = (unsigned short*)alloc(32768 * 2);  // [128][256]

    const int TPB = 256;
    int nb_nodes = (N_NODES + TPB - 1) / TPB;   // = NSB
    int nb_edges = (N_TOT + TPB - 1) / TPB;

    // ---- CSR build (by dst), parallel scan; weight convert ----
    zero_int_kernel<<<nb_nodes, TPB, 0, stream>>>(deg, N_NODES);
    wconv_kernel<<<320, TPB, 0, stream>>>(W1, W2, W3, W4, w1t, w2t, w3t, w4t);
    deg_hist_kernel<<<nb_edges, TPB, 0, stream>>>(ei, deg);
    block_scan_kernel<<<NSB, TPB, 0, stream>>>(deg, part, bsum);
    scan_bsum_kernel<<<1, TPB, 0, stream>>>(bsum);
    finalize_off_kernel<<<NSB, TPB, 0, stream>>>(part, bsum, off, cursor);
    fill_csr_kernel<<<nb_edges, TPB, 0, stream>>>(ei, cursor, csr_src);

    // agg grid: N_NODES * G lanes, G = hc/8
    auto agg_blocks = [](int hc) { return (N_NODES * (hc / 8) + 255) / 256; };

    // ---- Layer 1: 128 -> (8 heads x 32), ReLU ----
    gemm_mfma_kernel<128, 256, 8, 32, 32, 4, false>
        <<<(N_NODES + 31) / 32, TPB, 0, stream>>>(x, w1t, as1, ad1, h_buf, al_s, al_d);
    gat_agg_kernel<8, 32, true, true><<<agg_blocks(256), TPB, 0, stream>>>(h_buf, al_s, al_d, off, csr_src, b1, feat_a);

    // ---- Layer 2: 256 -> 32, 1 head ----
    gemm_mfma_kernel<256, 32, 1, 32, 64, 2, true>
        <<<(N_NODES + 63) / 64, TPB, 0, stream>>>(feat_a, w2t, as2, ad2, h_buf, al_s, al_d);
    gat_agg_kernel<1, 32, false, true><<<agg_blocks(32), TPB, 0, stream>>>(h_buf, al_s, al_d, off, csr_src, b2, feat_b);

    // ---- Layer 3: 32 -> (8 heads x 32), ReLU ----
    gemm_mfma_kernel<32, 256, 8, 32, 32, 4, true>
        <<<(N_NODES + 31) / 32, TPB, 0, stream>>>(feat_b, w3t, as3, ad3, h_buf, al_s, al_d);
    gat_agg_kernel<8, 32, true, true><<<agg_blocks(256), TPB, 0, stream>>>(h_buf, al_s, al_d, off, csr_src, b3, feat_a);

    // ---- Layer 4: 256 -> 128, 1 head ----
    gemm_mfma_kernel<256, 128, 1, 128, 32, 4, true>
        <<<(N_NODES + 31) / 32, TPB, 0, stream>>>(feat_a, w4t, as4, ad4, h_buf, al_s, al_d);
    gat_agg_kernel<1, 128, false, false><<<agg_blocks(128), TPB, 0, stream>>>(h_buf, al_s, al_d, off, csr_src, b4, d_out);
}